// Round 11
// baseline (136.540 us; speedup 1.0000x reference)
//
#include <hip/hip_runtime.h>
#include <hip/hip_bf16.h>

// Problem dims
#define Bn  8
#define Nn  128
#define Fn  128
#define Tfn 64
#define Tmn 256
#define Dfn 32
#define Dmn 128
#define En  64
#define Hn  128
#define TEn 64

// d_out layout (f32): [0,131072) noise_pred, [131072,262144) attn_weights, [262144] loss
#define OUT_AW_OFF   (Bn*Nn*Nn)
#define OUT_LOSS_OFF (Bn*Nn*Nn + Bn*Tfn*Tmn)

// ws layout (f32 slot units) — total 462,852 f32 = 1.85 MB
#define WS_G     0          // u16 B*Tm*Df
#define WS_BIAS  32768      // f32 B*Tm
#define WS_KVT   34816      // u16 B*H*Tm
#define WS_FWT   165888     // u16 H*Df   (fnirs_W^T [h][d], for cond-path q GEMM)
#define WS_NWT   167936     // u16 E*F
#define WS_HIT   172032     // u16 H*E
#define WS_HJT   176128     // u16 H*E
#define WS_CONDT 180224     // u16 H*H
#define WS_TVEC  188416     // f32 B*H
#define WS_PI    189440     // f32 B*N*H
#define WS_PJ    320512     // f32 B*N*H
#define WS_LOSS  451584     // f32 1
#define WS_MWT   451588     // u16 Dm*H transposed -> [h][d], 16384 u16 (16B-aligned)
#define WS_FWB   459780     // u16 48*H  ([fnirs_W rows; fnirs_b; 0], 6144 u16)

#define SCALE 0.08838834764831845f            // 1/sqrt(128)

typedef __attribute__((ext_vector_type(8))) short short8;   // 8 bf16 (4 VGPR)
typedef __attribute__((ext_vector_type(4))) float f32x4;

__device__ __forceinline__ unsigned short f2bf(float x) {
  __hip_bfloat16 h = __float2bfloat16(x);
  return __builtin_bit_cast(unsigned short, h);
}
__device__ __forceinline__ unsigned int pk2(float a, float b) {
  return (unsigned int)f2bf(a) | ((unsigned int)f2bf(b) << 16);
}

// ---------------------------------------------------------------------------
// Kernel 0 (k_wprep): all weight transposes/casts + tvec + loss zero.
// grid: 37 blocks x 128 threads.
// ---------------------------------------------------------------------------
__global__ __launch_bounds__(128) void k_wprep(
    const float* __restrict__ W1, const float* __restrict__ b1,
    const float* __restrict__ node_W, const float* __restrict__ fnirs_W,
    const float* __restrict__ fnirs_b, const float* __restrict__ music_W,
    const int* __restrict__ t,
    unsigned short* __restrict__ fwt, unsigned short* __restrict__ nwt,
    unsigned short* __restrict__ hit, unsigned short* __restrict__ hjt,
    unsigned short* __restrict__ condt, unsigned short* __restrict__ mwt,
    unsigned short* __restrict__ fwb, float* __restrict__ tvec,
    float* __restrict__ loss_acc)
{
  int blk = blockIdx.x, tid = threadIdx.x;
  if (blk < 8) {               // tvec[b][k] = b1[k] + sum_u te[u]*W1_time[u][k]
    int b = blk;
    __shared__ float te_l[TEn];
    if (tid < TEn/2) {
      int tcl = min(max(t[b], 0), Tfn - 1);
      float fr = (float)tcl * __expf(-(float)tid * (logf(10000.f) / (TEn/2 - 1)));
      te_l[tid] = __sinf(fr);
      te_l[tid + TEn/2] = __cosf(fr);
    }
    __syncthreads();
    float a = b1[tid];
    #pragma unroll 8
    for (int u = 0; u < TEn; u++) a = fmaf(te_l[u], W1[(2*En + 2 + Hn + u)*Hn + tid], a);
    tvec[b*Hn + tid] = a;
    if (b == 0 && tid == 0) loss_acc[0] = 0.f;
  } else if (blk < 16) {       // W1_cond^T[k][c]
    int q = blk - 8;
    #pragma unroll 4
    for (int i = 0; i < 16; i++) {
      int k = q*16 + i;
      condt[k*Hn + tid] = f2bf(W1[(2*En + 2 + tid)*Hn + k]);
    }
  } else if (blk < 20) {       // W1_hi^T[k][e]
    int q = blk - 16;
    int e = tid & 63, kh = tid >> 6;
    #pragma unroll 4
    for (int i = 0; i < 16; i++) {
      int k = q*32 + kh*16 + i;
      hit[k*En + e] = f2bf(W1[e*Hn + k]);
    }
  } else if (blk < 24) {       // W1_hj^T[k][e]
    int q = blk - 20;
    int e = tid & 63, kh = tid >> 6;
    #pragma unroll 4
    for (int i = 0; i < 16; i++) {
      int k = q*32 + kh*16 + i;
      hjt[k*En + e] = f2bf(W1[(En + e)*Hn + k]);
    }
  } else if (blk < 32) {       // node_W^T[e][f]
    int q = blk - 24;
    int fl = tid & 15, eh = tid >> 4;
    #pragma unroll 4
    for (int i = 0; i < 8; i++) {
      int e = eh*8 + i;
      nwt[e*Fn + q*16 + fl] = f2bf(node_W[(q*16 + fl)*En + e]);
    }
  } else if (blk < 34) {       // fnirs_W^T[h][d]  (cond-path q GEMM operand)
    int q = blk - 32;
    int d = tid & 31, hh = tid >> 5;
    #pragma unroll 4
    for (int i = 0; i < 16; i++) {
      int h = q*64 + hh*16 + i;
      fwt[h*Dfn + d] = f2bf(fnirs_W[d*Hn + h]);
    }
  } else if (blk < 36) {       // music_W^T[h][d]  (k_music kv-GEMM B operand)
    int q = blk - 34;          // q*64 h-rows each
    #pragma unroll 4
    for (int i = 0; i < 64; i++) {
      int h = q*64 + i;
      mwt[h*Dmn + tid] = f2bf(music_W[(size_t)tid*Hn + h]);
    }
  } else {                     // fwb[48][128]: rows 0..31 fnirs_W, 32 fnirs_b, 33..47 zero
    #pragma unroll 4
    for (int row = 0; row < 48; row++) {
      float v = (row < 32) ? fnirs_W[row*Hn + tid] : (row == 32 ? fnirs_b[tid] : 0.f);
      fwb[row*Hn + tid] = f2bf(v);
    }
  }
}

// ---------------------------------------------------------------------------
// Kernel 1 (k_music): MFMA chain  kv = fm@mwt + music_b ;  [G|bias] = kv@fwb.
// grid: B*(Tm/32) = 64 blocks x 256 threads (4 waves).
// Wave (rt = wv&1, cp = wv>>1). Frag conventions as k_attn (validated R6).
// ---------------------------------------------------------------------------
__global__ __launch_bounds__(256) void k_music(
    const float* __restrict__ feat_music, const float* __restrict__ music_b,
    const unsigned short* __restrict__ mwt, const unsigned short* __restrict__ fwb,
    unsigned short* __restrict__ kvT, unsigned short* __restrict__ G_bf,
    float* __restrict__ bias)
{
  __shared__ unsigned short fm_l[32][136];
  __shared__ unsigned short kv_l[32][136];

  int tid = threadIdx.x;
  int b = blockIdx.x >> 3;
  int m0 = (blockIdx.x & 7) << 5;

  // stage fm (32 x 128 f32 -> bf16): thread: row v>>3, 16 cols at (v&7)*16
  {
    int m = tid >> 3, c = (tid & 7) * 16;
    const float* src = feat_music + ((size_t)b*Tmn + m0 + m)*Dmn + c;
    float4 x0 = ((const float4*)src)[0];
    float4 x1 = ((const float4*)src)[1];
    float4 x2 = ((const float4*)src)[2];
    float4 x3 = ((const float4*)src)[3];
    uint4 pa, pb;
    pa.x = pk2(x0.x, x0.y); pa.y = pk2(x0.z, x0.w);
    pa.z = pk2(x1.x, x1.y); pa.w = pk2(x1.z, x1.w);
    pb.x = pk2(x2.x, x2.y); pb.y = pk2(x2.z, x2.w);
    pb.z = pk2(x3.x, x3.y); pb.w = pk2(x3.z, x3.w);
    uint4* dst = (uint4*)&fm_l[m][c];
    dst[0] = pa; dst[1] = pb;
  }
  __syncthreads();

  int lane = tid & 63, wv = tid >> 6;
  int col = lane & 15, kq = lane >> 4;
  int rt = wv & 1, cp = wv >> 1;

  short8 aF[4];
  #pragma unroll
  for (int ks = 0; ks < 4; ks++)
    aF[ks] = *(const short8*)&fm_l[rt*16 + col][ks*32 + kq*8];

  // ---- phase 1: kv col-tiles ht = cp*4 .. cp*4+3
  #pragma unroll
  for (int htl = 0; htl < 4; htl++) {
    int ht = cp*4 + htl;
    int h = ht*16 + col;
    f32x4 acc = {0.f,0.f,0.f,0.f};
    #pragma unroll
    for (int ks = 0; ks < 4; ks++) {
      short8 bfr = *(const short8*)(mwt + (size_t)h*Dmn + ks*32 + kq*8);
      acc = __builtin_amdgcn_mfma_f32_16x16x32_bf16(aF[ks], bfr, acc, 0, 0, 0);
    }
    float mb = music_b[h];
    unsigned short kvb[4];
    #pragma unroll
    for (int r = 0; r < 4; r++) {
      float v = acc[r] + mb;
      kvb[r] = f2bf(v);
      kv_l[rt*16 + kq*4 + r][h] = kvb[r];
    }
    // kvT[b][h][m]: 4 consecutive m -> one 8B store
    *(ushort4*)(kvT + ((size_t)b*Hn + h)*Tmn + m0 + rt*16 + kq*4) =
        make_ushort4(kvb[0], kvb[1], kvb[2], kvb[3]);
  }
  __syncthreads();

  // ---- phase 2: [G|bias] col-tiles; cp0 waves: ct {0,2}; cp1 waves: ct {1}
  short8 aK[4];
  #pragma unroll
  for (int ks = 0; ks < 4; ks++)
    aK[ks] = *(const short8*)&kv_l[rt*16 + col][ks*32 + kq*8];

  int nct = (cp == 0) ? 2 : 1;
  for (int cti = 0; cti < nct; cti++) {
    int ct = (cp == 0) ? cti*2 : 1;            // {0,2} or {1}
    f32x4 acc = {0.f,0.f,0.f,0.f};
    #pragma unroll
    for (int ks = 0; ks < 4; ks++) {
      short8 bfr = *(const short8*)(fwb + (size_t)(ct*16 + col)*Hn + ks*32 + kq*8);
      acc = __builtin_amdgcn_mfma_f32_16x16x32_bf16(aK[ks], bfr, acc, 0, 0, 0);
    }
    if (ct < 2) {
      #pragma unroll
      for (int r = 0; r < 4; r++)
        G_bf[((size_t)b*Tmn + m0 + rt*16 + kq*4 + r)*Dfn + ct*16 + col] =
            f2bf(acc[r] * SCALE);
    } else if (col == 0) {
      #pragma unroll
      for (int r = 0; r < 4; r++)
        bias[(size_t)b*Tmn + m0 + rt*16 + kq*4 + r] = acc[r] * SCALE;
    }
  }
}

// ---------------------------------------------------------------------------
// Kernel 2 (k_attn_cond): unchanged from round 10 (validated).
// ---------------------------------------------------------------------------
struct SmemAttn {
  unsigned short feat_l[Nn][40];
  unsigned short G_l[Tmn][40];
  float bias_l[Tmn];
  float aw_l[4][Tmn];
  float ent_l[4];
};
struct SmemCond {
  unsigned short featT_l[16][40];
  unsigned short A_l[16][264];
  unsigned short nf_l[16][136];
  unsigned short h_l[16][72];
  unsigned short cond_l[16][136];
  float sS[4][16];
  float tvec_l[Hn];
};
union __align__(16) SmemK2 {
  SmemAttn a;
  SmemCond c;
};

__global__ __launch_bounds__(256, 2) void k_attn_cond(
    const float* __restrict__ feat_fnirs, const float* __restrict__ node_feats,
    const float* __restrict__ node_b, const int* __restrict__ t,
    const unsigned short* __restrict__ G_bf, const float* __restrict__ bias,
    const unsigned short* __restrict__ kvT, const unsigned short* __restrict__ fwt,
    const unsigned short* __restrict__ nwt, const unsigned short* __restrict__ hit,
    const unsigned short* __restrict__ hjt, const unsigned short* __restrict__ condt,
    const float* __restrict__ tvec, float* __restrict__ Pi, float* __restrict__ Pj,
    float* __restrict__ aw_out, float* __restrict__ loss_acc)
{
  __shared__ SmemK2 smem;
  int tid = threadIdx.x;
  int lane = tid & 63, wv = tid >> 6;
  int col = lane & 15, kq = lane >> 4;

  if (blockIdx.x < 512) {
    // ================= attention =================
    int b = blockIdx.x >> 6, f = blockIdx.x & 63;
    {
      const uint4* gg = (const uint4*)(G_bf + (size_t)b*Tmn*Dfn);
      #pragma unroll
      for (int v0 = 0; v0 < 4; v0++) {
        int v = tid + v0*256;
        uint4 x = gg[v];
        int m = v >> 2, qt = v & 3;
        *((uint4*)&smem.a.G_l[m][qt*8]) = x;
      }
      smem.a.bias_l[tid] = bias[b*Tmn + tid];
      int n = tid >> 1, hf = tid & 1;
      const float* src = feat_fnirs + (((size_t)b*Nn + n)*Tfn + f)*Dfn + hf*16;
      float4 x0 = ((const float4*)src)[0];
      float4 x1 = ((const float4*)src)[1];
      float4 x2 = ((const float4*)src)[2];
      float4 x3 = ((const float4*)src)[3];
      uint4 pa, pb;
      pa.x = pk2(x0.x, x0.y); pa.y = pk2(x0.z, x0.w);
      pa.z = pk2(x1.x, x1.y); pa.w = pk2(x1.z, x1.w);
      pb.x = pk2(x2.x, x2.y); pb.y = pk2(x2.z, x2.w);
      pb.z = pk2(x3.x, x3.y); pb.w = pk2(x3.z, x3.w);
      uint4* dst = (uint4*)&smem.a.feat_l[n][hf*16];
      dst[0] = pa; dst[1] = pb;
    }
    __syncthreads();

    int n0 = wv * 32;
    short8 a0 = *(const short8*)&smem.a.feat_l[n0 + col][kq*8];
    short8 a1 = *(const short8*)&smem.a.feat_l[n0 + 16 + col][kq*8];

    float S0[4] = {0,0,0,0}, S1[4] = {0,0,0,0};
    float T0[4] = {0,0,0,0}, T1[4] = {0,0,0,0};
    float p0[16][4], p1[16][4];

    #pragma unroll
    for (int mt = 0; mt < 16; mt++) {
      short8 bfr = *(const short8*)&smem.a.G_l[mt*16 + col][kq*8];
      float bv = smem.a.bias_l[mt*16 + col];
      f32x4 c0 = __builtin_amdgcn_mfma_f32_16x16x32_bf16(a0, bfr, (f32x4){0.f,0.f,0.f,0.f}, 0, 0, 0);
      f32x4 c1 = __builtin_amdgcn_mfma_f32_16x16x32_bf16(a1, bfr, (f32x4){0.f,0.f,0.f,0.f}, 0, 0, 0);
      #pragma unroll
      for (int r = 0; r < 4; r++) {
        float sc = c0[r] + bv;
        float p = __expf(sc);
        S0[r] += p; T0[r] = fmaf(p, sc, T0[r]); p0[mt][r] = p;
        sc = c1[r] + bv;
        p = __expf(sc);
        S1[r] += p; T1[r] = fmaf(p, sc, T1[r]); p1[mt][r] = p;
      }
    }

    #pragma unroll
    for (int r = 0; r < 4; r++) {
      #pragma unroll
      for (int off = 1; off < 16; off <<= 1) {
        S0[r] += __shfl_xor(S0[r], off);
        S1[r] += __shfl_xor(S1[r], off);
        T0[r] += __shfl_xor(T0[r], off);
        T1[r] += __shfl_xor(T1[r], off);
      }
    }
    float i0v[4], i1v[4];
    #pragma unroll
    for (int r = 0; r < 4; r++) { i0v[r] = 1.f / S0[r]; i1v[r] = 1.f / S1[r]; }

    float ent = 0.f;
    if (col == 0) {
      #pragma unroll
      for (int r = 0; r < 4; r++) {
        ent += (__logf(S0[r]) - T0[r] * i0v[r]);
        ent += (__logf(S1[r]) - T1[r] * i1v[r]);
      }
    }
    ent += __shfl_xor(ent, 32); ent += __shfl_xor(ent, 16);
    ent += __shfl_xor(ent, 8);  ent += __shfl_xor(ent, 4);
    ent += __shfl_xor(ent, 2);  ent += __shfl_xor(ent, 1);
    if (lane == 0) smem.a.ent_l[wv] = ent;

    #pragma unroll
    for (int mt = 0; mt < 16; mt++) {
      float a = 0.f;
      #pragma unroll
      for (int r = 0; r < 4; r++) {
        a = fmaf(p0[mt][r], i0v[r], a);
        a = fmaf(p1[mt][r], i1v[r], a);
      }
      a += __shfl_xor(a, 16);
      a += __shfl_xor(a, 32);
      if (lane < 16) smem.a.aw_l[wv][mt*16 + lane] = a;
    }
    __syncthreads();

    float s = (smem.a.aw_l[0][tid] + smem.a.aw_l[1][tid]) +
              (smem.a.aw_l[2][tid] + smem.a.aw_l[3][tid]);
    aw_out[((size_t)b*Tfn + f)*Tmn + tid] = s * (1.f/(float)Nn);
    if (tid == 0)
      atomicAdd(loss_acc, (smem.a.ent_l[0] + smem.a.ent_l[1]) +
                          (smem.a.ent_l[2] + smem.a.ent_l[3]));
    return;
  }

  // ================= cond / Pi / Pj =================
  int blk = blockIdx.x - 512;
  int b = blk >> 3;
  int i0 = (blk & 7) << 4;
  int tcl = min(max(t[b], 0), Tfn - 1);

  if (tid < 128) {
    int i = tid >> 3, c = (tid & 7) * 4;
    const float* src = feat_fnirs + (((size_t)b*Nn + i0 + i)*Tfn + tcl)*Dfn + c;
    float4 x = *(const float4*)src;
    *(unsigned int*)&smem.c.featT_l[i][c]     = pk2(x.x, x.y);
    *(unsigned int*)&smem.c.featT_l[i][c + 2] = pk2(x.z, x.w);
    smem.c.tvec_l[tid] = tvec[b*Hn + tid];
  }
  {
    int i = tid >> 4, c = (tid & 15) * 8;
    const float* src = node_feats + ((size_t)b*Nn + i0 + i)*Fn + c;
    float4 x0 = ((const float4*)src)[0];
    float4 x1 = ((const float4*)src)[1];
    *(unsigned int*)&smem.c.nf_l[i][c]     = pk2(x0.x, x0.y);
    *(unsigned int*)&smem.c.nf_l[i][c + 2] = pk2(x0.z, x0.w);
    *(unsigned int*)&smem.c.nf_l[i][c + 4] = pk2(x1.x, x1.y);
    *(unsigned int*)&smem.c.nf_l[i][c + 6] = pk2(x1.z, x1.w);
  }
  __syncthreads();

  short8 a_feat = *(const short8*)&smem.c.featT_l[col][kq*8];

  // ---- phase 1: scores + softmax + A_bf
  float p[4][4];
  float Sp[4] = {0,0,0,0};
  #pragma unroll
  for (int mtl = 0; mtl < 4; mtl++) {
    int mt = wv*4 + mtl;
    short8 bg = *(const short8*)(G_bf + ((size_t)b*Tmn + mt*16 + col)*Dfn + kq*8);
    f32x4 c = __builtin_amdgcn_mfma_f32_16x16x32_bf16(a_feat, bg, (f32x4){0.f,0.f,0.f,0.f}, 0, 0, 0);
    float bv = bias[b*Tmn + mt*16 + col];
    #pragma unroll
    for (int r = 0; r < 4; r++) {
      float pp = __expf(c[r] + bv);
      p[mtl][r] = pp;
      Sp[r] += pp;
    }
  }
  #pragma unroll
  for (int r = 0; r < 4; r++) {
    float v = Sp[r];
    v += __shfl_xor(v, 1); v += __shfl_xor(v, 2);
    v += __shfl_xor(v, 4); v += __shfl_xor(v, 8);
    Sp[r] = v;
  }
  if (col == 0) {
    #pragma unroll
    for (int r = 0; r < 4; r++) smem.c.sS[wv][kq*4 + r] = Sp[r];
  }
  __syncthreads();
  float invS[4];
  #pragma unroll
  for (int r = 0; r < 4; r++)
    invS[r] = 1.f / (smem.c.sS[0][kq*4+r] + smem.c.sS[1][kq*4+r] +
                     smem.c.sS[2][kq*4+r] + smem.c.sS[3][kq*4+r]);
  #pragma unroll
  for (int mtl = 0; mtl < 4; mtl++) {
    #pragma unroll
    for (int r = 0; r < 4; r++)
      smem.c.A_l[kq*4 + r][(wv*4 + mtl)*16 + col] = f2bf(p[mtl][r] * invS[r]);
  }
  __syncthreads();

  // ---- phase 2: cond = q + ctx ; h (+node_b)
  f32x4 accC0 = {0.f,0.f,0.f,0.f}, accC1 = {0.f,0.f,0.f,0.f};
  {
    int ct0 = wv*2, ct1 = wv*2 + 1;
    short8 bq0 = *(const short8*)(fwt + (size_t)(ct0*16 + col)*Dfn + kq*8);
    short8 bq1 = *(const short8*)(fwt + (size_t)(ct1*16 + col)*Dfn + kq*8);
    accC0 = __builtin_amdgcn_mfma_f32_16x16x32_bf16(a_feat, bq0, accC0, 0, 0, 0);
    accC1 = __builtin_amdgcn_mfma_f32_16x16x32_bf16(a_feat, bq1, accC1, 0, 0, 0);
    #pragma unroll
    for (int ks = 0; ks < 8; ks++) {
      short8 aA = *(const short8*)&smem.c.A_l[col][ks*32 + kq*8];
      short8 bk0 = *(const short8*)(kvT + ((size_t)b*Hn + ct0*16 + col)*Tmn + ks*32 + kq*8);
      short8 bk1 = *(const short8*)(kvT + ((size_t)b*Hn + ct1*16 + col)*Tmn + ks*32 + kq*8);
      accC0 = __builtin_amdgcn_mfma_f32_16x16x32_bf16(aA, bk0, accC0, 0, 0, 0);
      accC1 = __builtin_amdgcn_mfma_f32_16x16x32_bf16(aA, bk1, accC1, 0, 0, 0);
    }
  }
  f32x4 accH = {0.f,0.f,0.f,0.f};
  #pragma unroll
  for (int ks = 0; ks < 4; ks++) {
    short8 aN = *(const short8*)&smem.c.nf_l[col][ks*32 + kq*8];
    short8 bn = *(const short8*)(nwt + (size_t)(wv*16 + col)*Fn + ks*32 + kq*8);
    accH = __builtin_amdgcn_mfma_f32_16x16x32_bf16(aN, bn, accH, 0, 0, 0);
  }
  float nb = node_b[wv*16 + col];
  #pragma unroll
  for (int r = 0; r < 4; r++) {
    smem.c.cond_l[kq*4 + r][(wv*2    )*16 + col] = f2bf(accC0[r]);
    smem.c.cond_l[kq*4 + r][(wv*2 + 1)*16 + col] = f2bf(accC1[r]);
    smem.c.h_l[kq*4 + r][wv*16 + col] = f2bf(accH[r] + nb);
  }
  __syncthreads();

  // ---- phase 3: Pi, Pj
  short8 aH[2];
  aH[0] = *(const short8*)&smem.c.h_l[col][kq*8];
  aH[1] = *(const short8*)&smem.c.h_l[col][32 + kq*8];
  #pragma unroll
  for (int ctl = 0; ctl < 2; ctl++) {
    int ct = wv*2 + ctl;
    f32x4 accPi = {0.f,0.f,0.f,0.f}, accPj = {0.f,0.f,0.f,0.f};
    #pragma unroll
    for (int ks = 0; ks < 2; ks++) {
      short8 bi_ = *(const short8*)(hit + (size_t)(ct*16 + col)*En + ks*32 + kq*8);
      short8 bj_ = *(const short8*)(hjt + (size_t)(ct*16 + col)*En + ks*32 + kq*8);
      accPi = __builtin_amdgcn_mfma_f32_16x16x32_bf16(aH[ks], bi_, accPi, 0, 0, 0);
      accPj = __builtin_amdgcn_mfma_f32_16x16x32_bf16(aH[ks], bj_, accPj, 0, 0, 0);
    }
    #pragma unroll
    for (int ks = 0; ks < 4; ks++) {
      short8 aC = *(const short8*)&smem.c.cond_l[col][ks*32 + kq*8];
      short8 bc = *(const short8*)(condt + (size_t)(ct*16 + col)*Hn + ks*32 + kq*8);
      accPj = __builtin_amdgcn_mfma_f32_16x16x32_bf16(aC, bc, accPj, 0, 0, 0);
    }
    float tv = smem.c.tvec_l[ct*16 + col];
    #pragma unroll
    for (int r = 0; r < 4; r++) {
      size_t row = (size_t)b*Nn + i0 + kq*4 + r;
      Pi[row*Hn + ct*16 + col] = accPi[r];
      Pj[row*Hn + ct*16 + col] = accPj[r] + tv;
    }
  }
}

// ---------------------------------------------------------------------------
// Kernel 3 (k_edge): unchanged from round 10 (validated).
// ---------------------------------------------------------------------------
__global__ __launch_bounds__(256) void k_edge(
    const float* __restrict__ adj, const float* __restrict__ gpre,
    const float* __restrict__ W1, const float* __restrict__ W2,
    const float* __restrict__ b2p, const float* __restrict__ Pi,
    const float* __restrict__ Pj, float* __restrict__ out,
    const float* __restrict__ loss_acc)
{
  int b  = blockIdx.x >> 6;
  int ib = (blockIdx.x >> 1) & 31;
  int jh = blockIdx.x & 1;
  int i0 = ib * 4;
  int tid = threadIdx.x;

  __shared__ float4 Pj_s4[64*32];
  __shared__ float4 Pi_s4[4*32];
  __shared__ float4 w2_s[32], wa_s[32], wg_s[32];

  {
    const float4* Pjg = (const float4*)(Pj + ((size_t)b*Nn + jh*64)*Hn);
    #pragma unroll
    for (int v0 = 0; v0 < 8; v0++) {
      int idx = tid + v0*256;
      int j = idx >> 5, c = idx & 31;
      Pj_s4[j*32 + (c ^ (j & 31))] = Pjg[j*32 + c];
    }
    if (tid < 128) {
      int r = tid >> 5, c = tid & 31;
      Pi_s4[r*32 + c] = ((const float4*)(Pi + ((size_t)b*Nn + i0 + r)*Hn))[c];
    } else if (tid < 160) {
      int c = tid - 128;
      w2_s[c] = ((const float4*)W2)[c];
      wa_s[c] = ((const float4*)(W1 + (2*En)*Hn))[c];
      wg_s[c] = ((const float4*)(W1 + (2*En + 1)*Hn))[c];
    }
  }
  __syncthreads();

  int r = tid >> 6, lane = tid & 63;
  int i = i0 + r, j = jh*64 + lane;
  float b2v = b2p[0];
  float adjv = adj [((size_t)b*Nn + i)*Nn + j];
  float gpv  = gpre[((size_t)b*Nn + i)*Nn + j];
  float a0 = 0.f, a1 = 0.f, a2 = 0.f, a3 = 0.f;
  #pragma unroll
  for (int c = 0; c < 32; c++) {
    float4 pj = Pj_s4[lane*32 + (c ^ (lane & 31))];
    float4 pi = Pi_s4[r*32 + c];
    float4 wa = wa_s[c], wg = wg_s[c], w2 = w2_s[c];
    float e0 = pi.x + pj.x + adjv*wa.x + gpv*wg.x;
    float e1 = pi.y + pj.y + adjv*wa.y + gpv*wg.y;
    float e2 = pi.z + pj.z + adjv*wa.z + gpv*wg.z;
    float e3 = pi.w + pj.w + adjv*wa.w + gpv*wg.w;
    a0 = fmaf(fmaxf(e0, 0.f), w2.x, a0);
    a1 = fmaf(fmaxf(e1, 0.f), w2.y, a1);
    a2 = fmaf(fmaxf(e2, 0.f), w2.z, a2);
    a3 = fmaf(fmaxf(e3, 0.f), w2.w, a3);
  }
  out[((size_t)b*Nn + i)*Nn + j] = (a0 + a1) + (a2 + a3) + b2v;

  if (blockIdx.x == 0 && tid == 0)
    out[OUT_LOSS_OFF] = loss_acc[0] * (1.f / (float)(Bn*Nn*Tfn));
}

// ---------------------------------------------------------------------------
extern "C" void kernel_launch(void* const* d_in, const int* in_sizes, int n_in,
                              void* d_out, int out_size, void* d_ws, size_t ws_size,
                              hipStream_t stream) {
  (void)in_sizes; (void)n_in; (void)out_size; (void)ws_size;
  const float* noisy_adj  = (const float*)d_in[0];
  const float* node_feats = (const float*)d_in[1];
  const float* feat_fnirs = (const float*)d_in[2];
  const float* feat_music = (const float*)d_in[3];
  const float* g_pre      = (const float*)d_in[4];
  const float* node_W     = (const float*)d_in[5];
  const float* node_b     = (const float*)d_in[6];
  const float* fnirs_W    = (const float*)d_in[7];
  const float* fnirs_b    = (const float*)d_in[8];
  const float* music_W    = (const float*)d_in[9];
  const float* music_b    = (const float*)d_in[10];
  const float* mlp_W1     = (const float*)d_in[11];
  const float* mlp_b1     = (const float*)d_in[12];
  const float* mlp_W2     = (const float*)d_in[13];
  const float* mlp_b2     = (const float*)d_in[14];
  const int*   t          = (const int*)d_in[15];

  float* out = (float*)d_out;
  float* ws = (float*)d_ws;
  unsigned short* g_ws    = (unsigned short*)(ws + WS_G);
  float*          bias_ws = ws + WS_BIAS;
  unsigned short* kvt_ws  = (unsigned short*)(ws + WS_KVT);
  unsigned short* fwt_ws  = (unsigned short*)(ws + WS_FWT);
  unsigned short* nwt_ws  = (unsigned short*)(ws + WS_NWT);
  unsigned short* hit_ws  = (unsigned short*)(ws + WS_HIT);
  unsigned short* hjt_ws  = (unsigned short*)(ws + WS_HJT);
  unsigned short* cndt_ws = (unsigned short*)(ws + WS_CONDT);
  float*          tvec_ws = ws + WS_TVEC;
  float*          Pi_ws   = ws + WS_PI;
  float*          Pj_ws   = ws + WS_PJ;
  float*          loss_ws = ws + WS_LOSS;
  unsigned short* mwt_ws  = (unsigned short*)(ws + WS_MWT);
  unsigned short* fwb_ws  = (unsigned short*)(ws + WS_FWB);

  k_wprep    <<<37,   128, 0, stream>>>(mlp_W1, mlp_b1, node_W, fnirs_W, fnirs_b,
                                        music_W, t, fwt_ws, nwt_ws, hit_ws, hjt_ws,
                                        cndt_ws, mwt_ws, fwb_ws, tvec_ws, loss_ws);
  k_music    <<<64,   256, 0, stream>>>(feat_music, music_b, mwt_ws, fwb_ws,
                                        kvt_ws, g_ws, bias_ws);
  k_attn_cond<<<576,  256, 0, stream>>>(feat_fnirs, node_feats, node_b, t,
                                        g_ws, bias_ws, kvt_ws, fwt_ws, nwt_ws,
                                        hit_ws, hjt_ws, cndt_ws, tvec_ws,
                                        Pi_ws, Pj_ws, out + OUT_AW_OFF, loss_ws);
  k_edge     <<<512,  256, 0, stream>>>(noisy_adj, g_pre, mlp_W1, mlp_W2, mlp_b2,
                                        Pi_ws, Pj_ws, out, loss_ws);
}